// Round 1
// baseline (215.636 us; speedup 1.0000x reference)
//
#include <hip/hip_runtime.h>
#include <hip/hip_bf16.h>

#define DEVINL __device__ __forceinline__

typedef __attribute__((ext_vector_type(8))) short short8;   // 8 bf16 (4 VGPRs)
typedef __attribute__((ext_vector_type(4))) float f32x4;    // MFMA acc

DEVINL float rcp_f(float x) { return __builtin_amdgcn_rcpf(x); }

// compiler-level memory barrier: forces LDS stores to be emitted and kills
// stale-value forwarding (R4-proven). No instruction generated; within-wave
// DS ordering is guaranteed by hardware (DS pipe is in-order per wave).
#define LDS_FENCE() __asm__ volatile("" ::: "memory")

// DPP cross-lane moves within 16-lane rows (VALU pipe, no DS latency).
template<int CTRL>
DEVINL float dpp_mov(float x) {
  return __int_as_float(__builtin_amdgcn_update_dpp(
      0, __float_as_int(x), CTRL, 0xF, 0xF, true));
}
// xor-16 exchange within each 32-lane half via ds_swizzle BitMode
// (offset = (16<<10) | 0x1F). Completes the 32-lane butterfly.
DEVINL float swz_xor16(float x) {
  return __int_as_float(__builtin_amdgcn_ds_swizzle(__float_as_int(x), 0x401F));
}
// 32-lane group reductions: proven 16-lane DPP butterfly + one xor16 stage.
DEVINL float group_sum(float x) {
  x += dpp_mov<0xB1>(x);   // quad_perm xor1
  x += dpp_mov<0x4E>(x);   // quad_perm xor2
  x += dpp_mov<0x141>(x);  // row_half_mirror
  x += dpp_mov<0x140>(x);  // row_mirror
  x += swz_xor16(x);       // xor16 across the two 16-rows
  return x;
}
DEVINL float group_min(float x) {
  x = fminf(x, dpp_mov<0xB1>(x));
  x = fminf(x, dpp_mov<0x4E>(x));
  x = fminf(x, dpp_mov<0x141>(x));
  x = fminf(x, dpp_mov<0x140>(x));
  x = fminf(x, swz_xor16(x));
  return x;
}
DEVINL float group_max(float x) {
  x = fmaxf(x, dpp_mov<0xB1>(x));
  x = fmaxf(x, dpp_mov<0x4E>(x));
  x = fmaxf(x, dpp_mov<0x141>(x));
  x = fmaxf(x, dpp_mov<0x140>(x));
  x = fmaxf(x, swz_xor16(x));
  return x;
}

// fp32 -> bf16 hi (round-half-up) + exact fp32 residual
DEVINL short bf_hi(float f, float& rem) {
  unsigned u = __float_as_uint(f);
  unsigned rh = (u + 0x8000u) >> 16;
  rem = f - __uint_as_float(rh << 16);
  return (short)rh;
}
DEVINL short bf_of(float f) {
  return (short)((__float_as_uint(f) + 0x8000u) >> 16);
}
DEVINL void cvt_hilo(float4 fa, float4 fb, short8& h, short8& lo) {
  float rm;
  h[0] = bf_hi(fa.x, rm); lo[0] = bf_of(rm);
  h[1] = bf_hi(fa.y, rm); lo[1] = bf_of(rm);
  h[2] = bf_hi(fa.z, rm); lo[2] = bf_of(rm);
  h[3] = bf_hi(fa.w, rm); lo[3] = bf_of(rm);
  h[4] = bf_hi(fb.x, rm); lo[4] = bf_of(rm);
  h[5] = bf_hi(fb.y, rm); lo[5] = bf_of(rm);
  h[6] = bf_hi(fb.z, rm); lo[6] = bf_of(rm);
  h[7] = bf_hi(fb.w, rm); lo[7] = bf_of(rm);
}
DEVINL f32x4 mfma_bf16(short8 a, short8 b, f32x4 c) {
  return __builtin_amdgcn_mfma_f32_16x16x32_bf16(a, b, c, 0, 0, 0);
}

// ---------- Householder step at compile-time pivot K ------------------------
// 32 lanes per molecule; lane l owns row l. Raw x staged to LDS BEFORE the
// norm reduction (roundtrip overlaps alpha/beta chain); pivot element fixed
// up in-register at constexpr index. Update uses folded scalars s_p, s_v
// (zero for frozen rows). Junk values only ever reach frozen columns of
// active rows, which are multiplied by masked (zero) v later — never read
// meaningfully again.
template<int K>
DEVINL void house_step(float (&r)[32], int l, int lane,
                       float* vbuf, float* pbuf, float* dbuf, float* ebuf) {
  constexpr int C0 = (K + 1) / 4;             // first float4 chunk touching v
  constexpr int PE = (K + 1) & 3;             // pivot element within chunk C0

  float xm = (l > K) ? r[K] : 0.0f;           // masked column K
  vbuf[l] = xm;                               // stage RAW x immediately
  LDS_FENCE();

  float x0 = __shfl(xm, (lane & 32) + (K + 1), 64);  // pivot value (no LDS dep)
  float nn = group_sum(xm * xm);

  float4 vc[8];                               // x chunks (read overlaps chain)
  #pragma unroll
  for (int c = C0; c < 8; ++c) vc[c] = *(const float4*)(vbuf + 4 * c);

  float alpha = -copysignf(sqrtf(nn), x0);    // new subdiagonal e_K
  float denom = nn - alpha * x0;              // >= 0
  float beta = (denom > 1e-20f) ? rcp_f(denom) : 0.0f;  // 2 / v'v

  float v = xm - ((l == K + 1) ? alpha : 0.0f);
  // fix the pivot element of the broadcast copy: v = x - alpha*e_{K+1}
  if constexpr (PE == 0)      vc[C0].x -= alpha;
  else if constexpr (PE == 1) vc[C0].y -= alpha;
  else if constexpr (PE == 2) vc[C0].z -= alpha;
  else                        vc[C0].w -= alpha;

  float a0 = 0.0f, a1 = 0.0f;                 // p_l = row_l . v (active cols)
  #pragma unroll
  for (int c = C0; c < 8; ++c) {
    a0 = fmaf(r[4 * c + 0], vc[c].x, a0); a1 = fmaf(r[4 * c + 1], vc[c].y, a1);
    a0 = fmaf(r[4 * c + 2], vc[c].z, a0); a1 = fmaf(r[4 * c + 3], vc[c].w, a1);
  }
  float p = a0 + a1;

  pbuf[l] = p;                                // store raw p = C*v
  LDS_FENCE();
  float G = group_sum(v * p);                 // overlaps p readback
  float c2 = 0.5f * beta * beta * G;

  // folded update scalars: r -= s_p*p[m] + s_v*v[m]   (== v*w[m] + w*v[m])
  float s_p = beta * v;                       // 0 for frozen rows (v masked)
  float s_v = (l > K) ? fmaf(-2.0f * c2, v, beta * p) : 0.0f;

  #pragma unroll
  for (int c = C0; c < 8; ++c) {
    float4 pc = *(const float4*)(pbuf + 4 * c);
    r[4 * c + 0] -= s_p * pc.x + s_v * vc[c].x;
    r[4 * c + 1] -= s_p * pc.y + s_v * vc[c].y;
    r[4 * c + 2] -= s_p * pc.z + s_v * vc[c].z;
    r[4 * c + 3] -= s_p * pc.w + s_v * vc[c].w;
  }

  if (l == K) { dbuf[K] = r[K]; ebuf[K] = alpha; }
}

template<int K>
DEVINL void house_all(float (&r)[32], int l, int lane,
                      float* vbuf, float* pbuf, float* dbuf, float* ebuf) {
  house_step<K>(r, l, lane, vbuf, pbuf, dbuf, ebuf);
  if constexpr (K < 30) house_all<K + 1>(r, l, lane, vbuf, pbuf, dbuf, ebuf);
}

__global__ __launch_bounds__(256, 4) void Correlation_85134841741354_kernel(
    const float* __restrict__ A, float* __restrict__ out, int M) {
  const int lane = threadIdx.x & 63;
  const int wave = threadIdx.x >> 6;
  const int q    = lane >> 4;            // Gram: 8-feature sub-chunk
  const int t    = lane & 15;            // Gram: MFMA row index
  const int a    = lane >> 5;            // eigensolve group (mol within wave)
  const int l    = lane & 31;            // row owned by this lane
  const int molbase = blockIdx.x * 8 + wave * 2;
  if (molbase >= M) return;              // M % 8 == 0

  // 2 C-tiles per wave (one per molecule), stride 36 (float4-aligned).
  // 4*2*1160*4B = 37.1 KB/block -> 4 blocks/CU (was 2 at 74 KB). Tile a's
  // memory is reused as group a's Householder scratch after readback.
  __shared__ float ldsT[4][2][32 * 36 + 8];

  // ---------------- Gram via MFMA (hi/lo bf16 split); NO readback in loop ----
  #pragma unroll 1
  for (int g = 0; g < 2; ++g) {
    const float* Am = A + (size_t)(molbase + g) * (32 * 128);
    f32x4 acc00 = {0.f, 0.f, 0.f, 0.f}, acc01 = {0.f, 0.f, 0.f, 0.f};
    f32x4 acc10 = {0.f, 0.f, 0.f, 0.f}, acc11 = {0.f, 0.f, 0.f, 0.f};
    #pragma unroll
    for (int c = 0; c < 4; ++c) {        // K chunks of 32 features
      const float* pr0 = Am + t * 128        + 32 * c + 8 * q;  // rows 0..15
      const float* pr1 = Am + (t + 16) * 128 + 32 * c + 8 * q;  // rows 16..31
      float4 fa0 = *(const float4*)(pr0);
      float4 fb0 = *(const float4*)(pr0 + 4);
      float4 fa1 = *(const float4*)(pr1);
      float4 fb1 = *(const float4*)(pr1 + 4);
      short8 h0, l0, h1, l1;
      cvt_hilo(fa0, fb0, h0, l0);
      cvt_hilo(fa1, fb1, h1, l1);
      // C = (hi+lo)(hi+lo)^T ~= hi hi^T + hi lo^T + lo hi^T  (drop lo lo^T)
      acc00 = mfma_bf16(h0, h0, acc00); acc00 = mfma_bf16(h0, l0, acc00); acc00 = mfma_bf16(l0, h0, acc00);
      acc01 = mfma_bf16(h0, h1, acc01); acc01 = mfma_bf16(h0, l1, acc01); acc01 = mfma_bf16(l0, h1, acc01);
      acc10 = mfma_bf16(h1, h0, acc10); acc10 = mfma_bf16(h1, l0, acc10); acc10 = mfma_bf16(l1, h0, acc10);
      acc11 = mfma_bf16(h1, h1, acc11); acc11 = mfma_bf16(h1, l1, acc11); acc11 = mfma_bf16(l1, h1, acc11);
    }
    // C/D layout: col = lane&15, row = (lane>>4)*4 + reg  [HW-verified]
    float* tg = &ldsT[wave][g][0];
    #pragma unroll
    for (int reg = 0; reg < 4; ++reg) {
      tg[(4 * q + reg) * 36 + t]           = acc00[reg];
      tg[(4 * q + reg) * 36 + 16 + t]      = acc01[reg];
      tg[(16 + 4 * q + reg) * 36 + t]      = acc10[reg];
      tg[(16 + 4 * q + reg) * 36 + 16 + t] = acc11[reg];
    }
  }
  LDS_FENCE();

  // readback: each 32-lane group reads its own molecule's rows (one row/lane)
  float* tq = &ldsT[wave][a][0];
  float r[32];
  #pragma unroll
  for (int c = 0; c < 8; ++c) {
    float4 x = *(const float4*)(tq + l * 36 + 4 * c);
    r[4 * c + 0] = x.x; r[4 * c + 1] = x.y;
    r[4 * c + 2] = x.z; r[4 * c + 3] = x.w;
  }
  LDS_FENCE();   // order readback reads before scratch writes (aliased memory)

  // Householder scratch carved from the (now dead) tile a; tiles are 1160
  // floats apart == 8-bank stagger between the wave's two groups -> every
  // 64-lane ds_write hits each bank exactly twice (2-way, free).
  float* vbuf = tq;
  float* pbuf = tq + 40;
  float* dbuf = tq + 80;
  float* ebuf = tq + 120;

  // ---------------- Householder tridiagonalization ---------------------------
  house_all<0>(r, l, lane, vbuf, pbuf, dbuf, ebuf);
  if (l == 31) { dbuf[31] = r[31]; ebuf[31] = 0.0f; }
  LDS_FENCE();

  // ---------------- Gershgorin bracket ---------------------------------------
  float d  = dbuf[l];
  float eh = ebuf[l];                        // ebuf[31] = 0
  float el = (l > 0) ? ebuf[l - 1] : 0.0f;
  float rad = fabsf(eh) + fabsf(el);
  float glo = group_min(d - rad);
  float ghi = group_max(d + rad);
  float lo = fmaxf(glo - 1e-3f, 0.0f);       // C = A A' is PSD
  float hi = ghi + 1e-3f;

  // tridiagonal into registers (uniform per group; broadcast LDS reads)
  float vd[32], ve2[32];
  #pragma unroll
  for (int c = 0; c < 8; ++c) {
    float4 dc = *(const float4*)(dbuf + 4 * c);
    float4 ec = *(const float4*)(ebuf + 4 * c);
    vd[4 * c + 0] = dc.x; vd[4 * c + 1] = dc.y;
    vd[4 * c + 2] = dc.z; vd[4 * c + 3] = dc.w;
    ve2[4 * c + 0] = ec.x * ec.x; ve2[4 * c + 1] = ec.y * ec.y;
    ve2[4 * c + 2] = ec.z * ec.z; ve2[4 * c + 3] = ec.w * ec.w;
  }

  // ---------------- Sturm bisection: 32 sigma points / round -----------------
  #pragma unroll
  for (int rr = 0; rr < 3; ++rr) {
    float stp = (hi - lo) * (1.0f / 33.0f);
    float sig = fmaf(stp, (float)(l + 1), lo);
    float qq = vd[0] - sig;
    int cnt = (qq < 0.0f) ? 1 : 0;
    #pragma unroll
    for (int i = 1; i < 32; ++i) {
      float qs = (fabsf(qq) < 1e-12f) ? ((qq < 0.0f) ? -1e-12f : 1e-12f) : qq;
      qq = (vd[i] - sig) - ve2[i - 1] * rcp_f(qs);
      cnt += (qq < 0.0f) ? 1 : 0;
    }
    unsigned long long m64 = __ballot(cnt >= 1);
    unsigned hm = (unsigned)(m64 >> (a * 32));
    int b = (hm == 0u) ? 32 : (__ffs(hm) - 1);
    float nhi = (b == 32) ? hi : fmaf(stp, (float)(b + 1), lo);
    lo = fmaf(stp, (float)b, lo);
    hi = nhi;
  }

  if (l == 0) out[molbase + a] = 0.5f * (lo + hi);
}

extern "C" void kernel_launch(void* const* d_in, const int* in_sizes, int n_in,
                              void* d_out, int out_size, void* d_ws, size_t ws_size,
                              hipStream_t stream) {
  const float* A = (const float*)d_in[0];
  float* out = (float*)d_out;
  int n_atoms = in_sizes[1];          // 262144
  int M = n_atoms / 32;               // 8192 molecules
  int blocks = (M + 7) / 8;           // 8 molecules per 256-thread block
  hipLaunchKernelGGL(Correlation_85134841741354_kernel,
                     dim3(blocks), dim3(256), 0, stream, A, out, M);
}